// Round 5
// baseline (208.250 us; speedup 1.0000x reference)
//
#include <hip/hip_runtime.h>
#include <math.h>

#define S_TOK 2048
#define NEXP  8
#define DDIM  768
#define HDIM  3072
#define KSEL  4096   // S * CAPACITY

typedef __attribute__((ext_vector_type(8))) short short8;
typedef __attribute__((ext_vector_type(4))) float f32x4;

__device__ __forceinline__ unsigned short f2bf(float f) {
  unsigned u = __float_as_uint(f);
  u += 0x7fffu + ((u >> 16) & 1u);   // round-to-nearest-even
  return (unsigned short)(u >> 16);
}

__device__ __forceinline__ float gelu_fast(float v) {
  float u = 0.7978845608028654f * (v + 0.044715f * v * v * v);
  float t = __expf(-2.0f * fabsf(u));
  float th = (1.0f - t) / (1.0f + t);
  th = copysignf(th, u);
  return 0.5f * v * (1.0f + th);
}

__global__ __launch_bounds__(256) void zero_kernel(float* __restrict__ p, int n) {
  int i = blockIdx.x * 256 + threadIdx.x;
  if (i < n) p[i] = 0.f;
}

__global__ __launch_bounds__(256) void convx_kernel(const float* __restrict__ x,
                                                    short* __restrict__ xb) {
  int i = (blockIdx.x * 256 + threadIdx.x) * 8;
  float4 a = *(const float4*)(x + i);
  float4 b = *(const float4*)(x + i + 4);
  short8 v;
  v[0] = (short)f2bf(a.x); v[1] = (short)f2bf(a.y);
  v[2] = (short)f2bf(a.z); v[3] = (short)f2bf(a.w);
  v[4] = (short)f2bf(b.x); v[5] = (short)f2bf(b.y);
  v[6] = (short)f2bf(b.z); v[7] = (short)f2bf(b.w);
  *(short8*)(xb + i) = v;
}

// ---------------- K1: gating (logits + softmax), exact fp32 ----------------
__global__ __launch_bounds__(256) void gate_kernel(
    const float* __restrict__ x, const float* __restrict__ gw,
    float* __restrict__ scores)
{
  int tid  = threadIdx.x;
  int lane = tid & 63;
  int wid  = tid >> 6;
  int token = blockIdx.x * 4 + wid;
  const float* xr = x + (size_t)token * DDIM;

  float acc[NEXP];
#pragma unroll
  for (int e = 0; e < NEXP; ++e) acc[e] = 0.f;

  for (int d = lane; d < DDIM; d += 64) {
    float xv = xr[d];
#pragma unroll
    for (int e = 0; e < NEXP; ++e) acc[e] += xv * gw[e * DDIM + d];
  }
#pragma unroll
  for (int e = 0; e < NEXP; ++e) {
    for (int off = 32; off; off >>= 1) acc[e] += __shfl_down(acc[e], off, 64);
  }
  if (lane == 0) {
    float m = acc[0];
#pragma unroll
    for (int e = 1; e < NEXP; ++e) m = fmaxf(m, acc[e]);
    float p[NEXP], s = 0.f;
#pragma unroll
    for (int e = 0; e < NEXP; ++e) { p[e] = expf(acc[e] - m); s += p[e]; }
    float inv = 1.0f / s;
#pragma unroll
    for (int e = 0; e < NEXP; ++e) scores[e * S_TOK + token] = p[e] * inv;
  }
}

// ---------------- K2: exact global top-k selection ----------------
__device__ unsigned block_scan_excl(unsigned v, volatile unsigned* wsum) {
  int tid = threadIdx.x, lane = tid & 63, wid = tid >> 6;
  __syncthreads();
  unsigned x = v;
#pragma unroll
  for (int off = 1; off < 64; off <<= 1) {
    unsigned t = __shfl_up(x, off, 64);
    if (lane >= off) x += t;
  }
  if (lane == 63) wsum[wid] = x;
  __syncthreads();
  if (tid < 64) {
    unsigned w = (lane < 16) ? wsum[lane] : 0u;
#pragma unroll
    for (int off = 1; off < 16; off <<= 1) {
      unsigned t = __shfl_up(w, off, 64);
      if (lane >= off) w += t;
    }
    if (lane < 16) wsum[lane] = w;
  }
  __syncthreads();
  unsigned woff = (wid > 0) ? wsum[wid - 1] : 0u;
  return woff + (x - v);
}

__global__ __launch_bounds__(1024) void select_kernel(
    const float* __restrict__ scores,
    int* __restrict__ tokenlist, float* __restrict__ slotgate,
    int* __restrict__ offsets)
{
  __shared__ unsigned cnt;
  __shared__ unsigned wsum[16];
  int tid = threadIdx.x;
  int base = tid * 16;

  float sv[16]; unsigned key[16];
#pragma unroll
  for (int j = 0; j < 16; ++j) {
    sv[j] = scores[base + j];
    key[j] = __float_as_uint(sv[j]);
  }

  unsigned lo = 0, hi = 0x3F800000u;
  while (lo < hi) {
    unsigned mid = lo + ((hi - lo + 1) >> 1);
    if (tid == 0) cnt = 0;
    __syncthreads();
    unsigned c = 0;
#pragma unroll
    for (int j = 0; j < 16; ++j) c += (key[j] >= mid) ? 1u : 0u;
    for (int off = 32; off; off >>= 1) c += __shfl_down(c, off, 64);
    if ((tid & 63) == 0) atomicAdd(&cnt, c);
    __syncthreads();
    unsigned tot = cnt;
    __syncthreads();
    if (tot >= (unsigned)KSEL) lo = mid; else hi = mid - 1;
  }
  unsigned V = lo;

  if (tid == 0) cnt = 0;
  __syncthreads();
  {
    unsigned c = 0;
#pragma unroll
    for (int j = 0; j < 16; ++j) c += (key[j] > V) ? 1u : 0u;
    for (int off = 32; off; off >>= 1) c += __shfl_down(c, off, 64);
    if ((tid & 63) == 0) atomicAdd(&cnt, c);
  }
  __syncthreads();
  int need = KSEL - (int)cnt;
  __syncthreads();

  unsigned tloc = 0;
#pragma unroll
  for (int j = 0; j < 16; ++j) tloc += (key[j] == V) ? 1u : 0u;
  unsigned texcl = block_scan_excl(tloc, wsum);

  unsigned selmask = 0, sloc = 0, trun = texcl;
#pragma unroll
  for (int j = 0; j < 16; ++j) {
    bool f;
    if (key[j] > V) f = true;
    else if (key[j] == V) { f = ((int)trun < need); ++trun; }
    else f = false;
    if (f) { selmask |= (1u << j); ++sloc; }
  }
  unsigned sexcl = block_scan_excl(sloc, wsum);

  // expert e starts at flat index e*2048 == thread e*128
  if ((tid & 127) == 0) offsets[tid >> 7] = (int)sexcl;
  if (tid == 0) offsets[NEXP] = KSEL;

  unsigned p = sexcl;
#pragma unroll
  for (int j = 0; j < 16; ++j) {
    int i = base + j;
    if (selmask & (1u << j)) {
      tokenlist[p] = i & (S_TOK - 1);
      slotgate[p] = sv[j];
      ++p;
    }
  }
}

// ------- K3/K4: bf16 MFMA grouped GEMM, 128x128 tile, BK=32, B-prefetch depth 2 -------
// grid = (expert=8, N/128, slots) -> linear_id % 8 == expert (XCD affinity)
// MODE 1: slots z=tile(16);            A = xbf gathered (K=768); hbuf = gelu(A@W1+b1), bf16
// MODE 2: slots z=tile(16)*4+split(4); A = hbuf (K=3072/4);      y[token] += gate*(A@W2+b2)
template <int MODE>
__global__ __launch_bounds__(256) void moe_mfma(
    const short* __restrict__ Abase, const float* __restrict__ W,
    const float* __restrict__ bias, void* __restrict__ outp,
    const int* __restrict__ offsets, const int* __restrict__ tokenlist,
    const float* __restrict__ slotgate)
{
  const int e = (int)blockIdx.x;
  const int K = (MODE == 1) ? DDIM : HDIM;
  const int N = (MODE == 1) ? HDIM : DDIM;
  const int tile  = (MODE == 1) ? (int)blockIdx.z : ((int)blockIdx.z >> 2);
  const int split = (MODE == 1) ? 0 : ((int)blockIdx.z & 3);
  const int klen  = 768;                  // DDIM and HDIM/4
  const int kb = split * klen;

  const int r0 = offsets[e];
  const int rows = offsets[e + 1] - r0;
  const int rowbase = tile << 7;
  if (rowbase >= rows) return;
  int vr = rows - rowbase; if (vr > 128) vr = 128;
  const int colbase = (int)blockIdx.y << 7;

  __shared__ short As[128 * 40];
  __shared__ short Bb[128 * 40];

  const int tid = threadIdx.x;
  const int lane = tid & 63;
  const int wid = tid >> 6;
  const int wr = (wid >> 1) << 6;
  const int wc = (wid & 1) << 6;
  const int l15 = lane & 15;
  const int lq = lane >> 4;

  // A staging: row ar = tid>>1, k-offset ak = (tid&1)*16
  const int ar = tid >> 1;
  const int ak = (tid & 1) << 4;
  const short* arow;
  {
    int cr = (ar < vr) ? ar : (vr - 1);
    if (MODE == 1) arow = Abase + (size_t)tokenlist[r0 + rowbase + cr] * DDIM;
    else           arow = Abase + (size_t)(r0 + rowbase + cr) * HDIM + kb;
  }
  // B staging: col bn = tid&127, k-half bk = (tid>>7)*16; coalesced across lanes
  const int bn = tid & 127;
  const int bk = (tid >> 7) << 4;
  const float* wcol = W + (size_t)e * K * N + colbase + bn;

  f32x4 acc[4][4];
#pragma unroll
  for (int i = 0; i < 4; ++i)
#pragma unroll
    for (int j = 0; j < 4; ++j) acc[i][j] = (f32x4){0.f, 0.f, 0.f, 0.f};

  short8 av0, av1;
  float bwA[16], bwB[16];
  {
    const short* ap = arow + ak;
    av0 = *(const short8*)(ap);
    av1 = *(const short8*)(ap + 8);
    const float* wpA = wcol + (size_t)(kb + bk) * N;
    const float* wpB = wcol + (size_t)(kb + 32 + bk) * N;
#pragma unroll
    for (int j = 0; j < 16; ++j) bwA[j] = wpA[(size_t)j * N];
#pragma unroll
    for (int j = 0; j < 16; ++j) bwB[j] = wpB[(size_t)j * N];
  }

#define WRITE_LDS(BW)                                            \
  {                                                              \
    *(short8*)&As[ar * 40 + ak] = av0;                           \
    *(short8*)&As[ar * 40 + ak + 8] = av1;                       \
    short8 b0, b1;                                               \
    _Pragma("unroll")                                            \
    for (int m = 0; m < 8; ++m) {                                \
      b0[m] = (short)f2bf(BW[m]);                                \
      b1[m] = (short)f2bf(BW[m + 8]);                            \
    }                                                            \
    *(short8*)&Bb[bn * 40 + bk] = b0;                            \
    *(short8*)&Bb[bn * 40 + bk + 8] = b1;                        \
  }

#define LOAD_A(KN)                                               \
  {                                                              \
    const short* ap = arow + (KN) + ak;                          \
    av0 = *(const short8*)(ap);                                  \
    av1 = *(const short8*)(ap + 8);                              \
  }

#define LOAD_B(BW, KN)                                           \
  {                                                              \
    const float* wp = wcol + (size_t)(kb + (KN) + bk) * N;       \
    _Pragma("unroll")                                            \
    for (int j = 0; j < 16; ++j) BW[j] = wp[(size_t)j * N];      \
  }

#define FRAG_MFMA()                                              \
  {                                                              \
    short8 af[4], bfr[4];                                        \
    _Pragma("unroll")                                            \
    for (int i = 0; i < 4; ++i)                                  \
      af[i] = *(const short8*)&As[(wr + i * 16 + l15) * 40 + lq * 8]; \
    _Pragma("unroll")                                            \
    for (int j = 0; j < 4; ++j)                                  \
      bfr[j] = *(const short8*)&Bb[(wc + j * 16 + l15) * 40 + lq * 8]; \
    _Pragma("unroll")                                            \
    for (int i = 0; i < 4; ++i)                                  \
      _Pragma("unroll")                                          \
      for (int j = 0; j < 4; ++j)                                \
        acc[i][j] = __builtin_amdgcn_mfma_f32_16x16x32_bf16(af[i], bfr[j], acc[i][j], 0, 0, 0); \
  }

#pragma unroll 1
  for (int k0 = 0; k0 < klen; k0 += 64) {
    // ---- sub-step A: consume (avA@k0, bwA@k0) ----
    __syncthreads();
    WRITE_LDS(bwA);
    __syncthreads();
    LOAD_A(k0 + 32);                        // always valid (k0 <= klen-64)
    { int kn = k0 + 64; if (kn >= klen) kn = k0; LOAD_B(bwA, kn); }
    FRAG_MFMA();
    // ---- sub-step B: consume (avA@k0+32, bwB@k0+32) ----
    __syncthreads();
    WRITE_LDS(bwB);
    __syncthreads();
    { int kn = k0 + 64; if (kn >= klen) kn = k0; LOAD_A(kn); }
    { int kn = k0 + 96; if (kn >= klen) kn = k0; LOAD_B(bwB, kn); }
    FRAG_MFMA();
  }

  if (MODE == 1) {
    short* hb = (short*)outp;
    const float* bp = bias + (size_t)e * N + colbase;
#pragma unroll
    for (int i = 0; i < 4; ++i) {
      int rb = wr + i * 16 + lq * 4;
#pragma unroll
      for (int j = 0; j < 4; ++j) {
        int col = wc + j * 16 + l15;
        float bvv = bp[col];
#pragma unroll
        for (int p = 0; p < 4; ++p) {
          int r = rb + p;
          if (r < vr)
            hb[(size_t)(r0 + rowbase + r) * HDIM + colbase + col] =
                (short)f2bf(gelu_fast(acc[i][j][p] + bvv));
        }
      }
    }
  } else {
    float* y = (float*)outp;
    const float* bp = bias + (size_t)e * N + colbase;
#pragma unroll
    for (int i = 0; i < 4; ++i) {
      int rb = wr + i * 16 + lq * 4;
#pragma unroll
      for (int p = 0; p < 4; ++p) {
        int r = rb + p;
        if (r < vr) {
          int gi = r0 + rowbase + r;
          float g = slotgate[gi];
          float* yrow = y + (size_t)tokenlist[gi] * N + colbase;
#pragma unroll
          for (int j = 0; j < 4; ++j) {
            int col = wc + j * 16 + l15;
            float v = acc[i][j][p] + (split == 0 ? bp[col] : 0.f);
            atomicAdd(&yrow[col], g * v);
          }
        }
      }
    }
  }
}

extern "C" void kernel_launch(void* const* d_in, const int* in_sizes, int n_in,
                              void* d_out, int out_size, void* d_ws, size_t ws_size,
                              hipStream_t stream) {
  const float* x  = (const float*)d_in[0];
  const float* gw = (const float*)d_in[1];
  const float* w1 = (const float*)d_in[2];
  const float* b1 = (const float*)d_in[3];
  const float* w2 = (const float*)d_in[4];
  const float* b2 = (const float*)d_in[5];
  float* y = (float*)d_out;

  char* ws = (char*)d_ws;
  float* scores    = (float*)(ws);                    // 64 KB
  int*   tokenlist = (int*)(ws + (64 << 10));         // 16 KB
  float* slotgate  = (float*)(ws + (80 << 10));       // 16 KB
  int*   offsets   = (int*)(ws + (96 << 10));         // 9 ints
  short* xbf       = (short*)(ws + (128 << 10));      // 3 MB
  short* hbuf      = (short*)(ws + (128 << 10) + (size_t)S_TOK * DDIM * 2);  // 24 MB

  zero_kernel<<<(out_size + 255) / 256, 256, 0, stream>>>(y, out_size);
  convx_kernel<<<S_TOK * DDIM / 2048, 256, 0, stream>>>(x, xbf);
  gate_kernel<<<S_TOK / 4, 256, 0, stream>>>(x, gw, scores);
  select_kernel<<<1, 1024, 0, stream>>>(scores, tokenlist, slotgate, offsets);

  dim3 g1(NEXP, HDIM / 128, 16);   // expert fastest -> id%8 == expert (XCD affinity)
  moe_mfma<1><<<g1, 256, 0, stream>>>(xbf, w1, b1, hbuf, offsets, tokenlist, slotgate);
  dim3 g2(NEXP, DDIM / 128, 64);   // z = tile*4 + ksplit
  moe_mfma<2><<<g2, 256, 0, stream>>>(hbuf, w2, b2, y, offsets, tokenlist, slotgate);
}

// Round 6
// 196.132 us; speedup vs baseline: 1.0618x; 1.0618x over previous
//
#include <hip/hip_runtime.h>
#include <math.h>

#define S_TOK 2048
#define NEXP  8
#define DDIM  768
#define HDIM  3072
#define KSEL  4096   // S * CAPACITY

typedef __attribute__((ext_vector_type(8))) short short8;
typedef __attribute__((ext_vector_type(4))) float f32x4;
typedef __attribute__((ext_vector_type(2))) unsigned int u32x2;

__device__ __forceinline__ unsigned short f2bf(float f) {
  unsigned u = __float_as_uint(f);
  u += 0x7fffu + ((u >> 16) & 1u);   // round-to-nearest-even
  return (unsigned short)(u >> 16);
}

__device__ __forceinline__ float gelu_fast(float v) {
  float u = 0.7978845608028654f * (v + 0.044715f * v * v * v);
  float t = __expf(-2.0f * fabsf(u));
  float th = (1.0f - t) / (1.0f + t);
  th = copysignf(th, u);
  return 0.5f * v * (1.0f + th);
}

__global__ __launch_bounds__(256) void convx_kernel(const float* __restrict__ x,
                                                    short* __restrict__ xb) {
  int i = (blockIdx.x * 256 + threadIdx.x) * 8;
  float4 a = *(const float4*)(x + i);
  float4 b = *(const float4*)(x + i + 4);
  short8 v;
  v[0] = (short)f2bf(a.x); v[1] = (short)f2bf(a.y);
  v[2] = (short)f2bf(a.z); v[3] = (short)f2bf(a.w);
  v[4] = (short)f2bf(b.x); v[5] = (short)f2bf(b.y);
  v[6] = (short)f2bf(b.z); v[7] = (short)f2bf(b.w);
  *(short8*)(xb + i) = v;
}

// ---------------- K1: gating (logits + softmax), exact fp32 ----------------
__global__ __launch_bounds__(256) void gate_kernel(
    const float* __restrict__ x, const float* __restrict__ gw,
    float* __restrict__ scores)
{
  int tid  = threadIdx.x;
  int lane = tid & 63;
  int wid  = tid >> 6;
  int token = blockIdx.x * 4 + wid;
  const float* xr = x + (size_t)token * DDIM;

  float acc[NEXP];
#pragma unroll
  for (int e = 0; e < NEXP; ++e) acc[e] = 0.f;

  for (int d = lane; d < DDIM; d += 64) {
    float xv = xr[d];
#pragma unroll
    for (int e = 0; e < NEXP; ++e) acc[e] += xv * gw[e * DDIM + d];
  }
#pragma unroll
  for (int e = 0; e < NEXP; ++e) {
    for (int off = 32; off; off >>= 1) acc[e] += __shfl_down(acc[e], off, 64);
  }
  if (lane == 0) {
    float m = acc[0];
#pragma unroll
    for (int e = 1; e < NEXP; ++e) m = fmaxf(m, acc[e]);
    float p[NEXP], s = 0.f;
#pragma unroll
    for (int e = 0; e < NEXP; ++e) { p[e] = expf(acc[e] - m); s += p[e]; }
    float inv = 1.0f / s;
#pragma unroll
    for (int e = 0; e < NEXP; ++e) scores[e * S_TOK + token] = p[e] * inv;
  }
}

// ---------------- K2: exact global top-k selection ----------------
__device__ unsigned block_scan_excl(unsigned v, volatile unsigned* wsum) {
  int tid = threadIdx.x, lane = tid & 63, wid = tid >> 6;
  __syncthreads();
  unsigned x = v;
#pragma unroll
  for (int off = 1; off < 64; off <<= 1) {
    unsigned t = __shfl_up(x, off, 64);
    if (lane >= off) x += t;
  }
  if (lane == 63) wsum[wid] = x;
  __syncthreads();
  if (tid < 64) {
    unsigned w = (lane < 16) ? wsum[lane] : 0u;
#pragma unroll
    for (int off = 1; off < 16; off <<= 1) {
      unsigned t = __shfl_up(w, off, 64);
      if (lane >= off) w += t;
    }
    if (lane < 16) wsum[lane] = w;
  }
  __syncthreads();
  unsigned woff = (wid > 0) ? wsum[wid - 1] : 0u;
  return woff + (x - v);
}

__global__ __launch_bounds__(1024) void select_kernel(
    const float* __restrict__ scores,
    int* __restrict__ tokenlist, float* __restrict__ slotgate,
    int* __restrict__ offsets, int* __restrict__ posmap)
{
  __shared__ unsigned cnt;
  __shared__ unsigned wsum[16];
  int tid = threadIdx.x;
  int base = tid * 16;

  float sv[16]; unsigned key[16];
#pragma unroll
  for (int j = 0; j < 16; ++j) {
    sv[j] = scores[base + j];
    key[j] = __float_as_uint(sv[j]);
  }

  unsigned lo = 0, hi = 0x3F800000u;
  while (lo < hi) {
    unsigned mid = lo + ((hi - lo + 1) >> 1);
    if (tid == 0) cnt = 0;
    __syncthreads();
    unsigned c = 0;
#pragma unroll
    for (int j = 0; j < 16; ++j) c += (key[j] >= mid) ? 1u : 0u;
    for (int off = 32; off; off >>= 1) c += __shfl_down(c, off, 64);
    if ((tid & 63) == 0) atomicAdd(&cnt, c);
    __syncthreads();
    unsigned tot = cnt;
    __syncthreads();
    if (tot >= (unsigned)KSEL) lo = mid; else hi = mid - 1;
  }
  unsigned V = lo;

  if (tid == 0) cnt = 0;
  __syncthreads();
  {
    unsigned c = 0;
#pragma unroll
    for (int j = 0; j < 16; ++j) c += (key[j] > V) ? 1u : 0u;
    for (int off = 32; off; off >>= 1) c += __shfl_down(c, off, 64);
    if ((tid & 63) == 0) atomicAdd(&cnt, c);
  }
  __syncthreads();
  int need = KSEL - (int)cnt;
  __syncthreads();

  unsigned tloc = 0;
#pragma unroll
  for (int j = 0; j < 16; ++j) tloc += (key[j] == V) ? 1u : 0u;
  unsigned texcl = block_scan_excl(tloc, wsum);

  unsigned selmask = 0, sloc = 0, trun = texcl;
#pragma unroll
  for (int j = 0; j < 16; ++j) {
    bool f;
    if (key[j] > V) f = true;
    else if (key[j] == V) { f = ((int)trun < need); ++trun; }
    else f = false;
    if (f) { selmask |= (1u << j); ++sloc; }
  }
  unsigned sexcl = block_scan_excl(sloc, wsum);

  // expert e starts at flat index e*2048 == thread e*128
  if ((tid & 127) == 0) offsets[tid >> 7] = (int)sexcl;
  if (tid == 0) offsets[NEXP] = KSEL;

  unsigned p = sexcl;
#pragma unroll
  for (int j = 0; j < 16; ++j) {
    int i = base + j;
    if (selmask & (1u << j)) {
      posmap[i] = (int)p;
      tokenlist[p] = i & (S_TOK - 1);
      slotgate[p] = sv[j];
      ++p;
    } else {
      posmap[i] = -1;
    }
  }
}

// ------- K3/K4: bf16 MFMA grouped GEMM, 128x128 tile, BK=32 -------
// B path: coalesced float4 W loads -> bf16 pack -> subtiled LDS [k/4][n/16][4][16]
//         -> fragments via ds_read_b64_tr_b16 (HW transpose).
// grid = (expert=8, N/128, slots) -> linear_id % 8 == expert (XCD affinity)
// MODE 1: z=tile(16);            A = xbf gathered (K=768); hbuf = gelu(A@W1+b1), bf16
// MODE 2: z=tile(16)*2+split(2); A = hbuf (K=3072/2);      outbuf[split] = A@W2 (+b2 on split0)
template <int MODE>
__global__ __launch_bounds__(256) void moe_mfma(
    const short* __restrict__ Abase, const float* __restrict__ W,
    const float* __restrict__ bias, void* __restrict__ outp,
    const int* __restrict__ offsets, const int* __restrict__ tokenlist)
{
  const int e = (int)blockIdx.x;
  const int K = (MODE == 1) ? DDIM : HDIM;
  const int N = (MODE == 1) ? HDIM : DDIM;
  const int tile  = (MODE == 1) ? (int)blockIdx.z : ((int)blockIdx.z >> 1);
  const int split = (MODE == 1) ? 0 : ((int)blockIdx.z & 1);
  const int klen  = (MODE == 1) ? DDIM : (HDIM / 2);
  const int kb = split * klen;

  const int r0 = offsets[e];
  const int rows = offsets[e + 1] - r0;
  const int rowbase = tile << 7;
  if (rowbase >= rows) return;
  int vr = rows - rowbase; if (vr > 128) vr = 128;
  const int colbase = (int)blockIdx.y << 7;

  __shared__ short As[128 * 40];                 // 10240 B, [row][40-padded k]
  __shared__ __align__(16) short Bs[32 * 128];   // 8192 B, 64 tiles of 4x16 bf16
  const unsigned bs_lds = (unsigned)(uintptr_t)&Bs[0];

  const int tid = threadIdx.x;
  const int lane = tid & 63;
  const int wid = tid >> 6;
  const int wr = (wid >> 1) << 6;
  const int wc = (wid & 1) << 6;
  const int l15 = lane & 15;
  const int lq = lane >> 4;

  // A staging: row ar = tid>>1, k-offset ak = (tid&1)*16 (proven path)
  const int ar = tid >> 1;
  const int ak = (tid & 1) << 4;
  const short* arow;
  {
    int cr = (ar < vr) ? ar : (vr - 1);
    if (MODE == 1) arow = Abase + (size_t)tokenlist[r0 + rowbase + cr] * DDIM;
    else           arow = Abase + (size_t)(r0 + rowbase + cr) * HDIM + kb;
  }

  // B staging: k-row sk = tid>>3, n-group g8 = tid&7 (16 cols = 4 float4s)
  const int sk = tid >> 3;
  const int g8 = tid & 7;
  const float* wsrc = W + (size_t)e * K * N + (size_t)kb * N + colbase + g8 * 16;
  // LDS write base: tile (sk>>2, g8), row sk&3  (shorts)
  short* bwr = (short*)Bs + ((((sk >> 2) << 3) + g8) << 6) + ((sk & 3) << 4);

  f32x4 acc[4][4];
#pragma unroll
  for (int i = 0; i < 4; ++i)
#pragma unroll
    for (int j = 0; j < 4; ++j) acc[i][j] = (f32x4){0.f, 0.f, 0.f, 0.f};

  short8 avA0, avA1;
  float4 bw[4];
  {
    avA0 = *(const short8*)(arow + ak);
    avA1 = *(const short8*)(arow + ak + 8);
    const float* wp = wsrc + (size_t)sk * N;
#pragma unroll
    for (int q = 0; q < 4; ++q) bw[q] = *(const float4*)(wp + 4 * q);
  }

#pragma unroll 1
  for (int k0 = 0; k0 < klen; k0 += 32) {
    __syncthreads();
    // ---- write staged tiles to LDS ----
    *(short8*)&As[ar * 40 + ak] = avA0;
    *(short8*)&As[ar * 40 + ak + 8] = avA1;
#pragma unroll
    for (int q = 0; q < 4; ++q) {
      u32x2 pk;
      pk[0] = (unsigned)f2bf(bw[q].x) | ((unsigned)f2bf(bw[q].y) << 16);
      pk[1] = (unsigned)f2bf(bw[q].z) | ((unsigned)f2bf(bw[q].w) << 16);
      *(u32x2*)(bwr + 4 * q) = pk;
    }
    __syncthreads();
    // ---- prefetch next K-step ----
    if (k0 + 32 < klen) {
      avA0 = *(const short8*)(arow + k0 + 32 + ak);
      avA1 = *(const short8*)(arow + k0 + 32 + ak + 8);
      const float* wp = wsrc + (size_t)(k0 + 32 + sk) * N;
#pragma unroll
      for (int q = 0; q < 4; ++q) bw[q] = *(const float4*)(wp + 4 * q);
    }
    // ---- fragments ----
    short8 af[4], bfr[4];
#pragma unroll
    for (int i = 0; i < 4; ++i)
      af[i] = *(const short8*)&As[(wr + i * 16 + l15) * 40 + lq * 8];
#pragma unroll
    for (int j = 0; j < 4; ++j) {
      // tile index = (lq*2)*8 + ((wc>>4)+j); second tr read at +8 tiles (=1024 B)
      unsigned off = bs_lds + ((unsigned)((lq << 4) + (wc >> 4) + j) << 7) +
                     ((unsigned)l15 << 3);
      union { short8 s; u32x2 u[2]; } fb;
      asm volatile("ds_read_b64_tr_b16 %0, %2 offset:0\n\t"
                   "ds_read_b64_tr_b16 %1, %2 offset:1024"
                   : "=&v"(fb.u[0]), "=&v"(fb.u[1]) : "v"(off));
      bfr[j] = fb.s;
    }
    asm volatile("s_waitcnt lgkmcnt(0)" ::: "memory");
    __builtin_amdgcn_sched_barrier(0);
#pragma unroll
    for (int i = 0; i < 4; ++i)
#pragma unroll
      for (int j = 0; j < 4; ++j)
        acc[i][j] = __builtin_amdgcn_mfma_f32_16x16x32_bf16(af[i], bfr[j], acc[i][j], 0, 0, 0);
  }

  if (MODE == 1) {
    short* hb = (short*)outp;
    const float* bp = bias + (size_t)e * N + colbase;
#pragma unroll
    for (int i = 0; i < 4; ++i) {
      int rb = wr + i * 16 + lq * 4;
#pragma unroll
      for (int j = 0; j < 4; ++j) {
        int col = wc + j * 16 + l15;
        float bvv = bp[col];
#pragma unroll
        for (int p = 0; p < 4; ++p) {
          int r = rb + p;
          if (r < vr)
            hb[(size_t)(r0 + rowbase + r) * HDIM + colbase + col] =
                (short)f2bf(gelu_fast(acc[i][j][p] + bvv));
        }
      }
    }
  } else {
    float* ob = (float*)outp + (size_t)split * KSEL * DDIM;
    const float* bp = bias + (size_t)e * N + colbase;
#pragma unroll
    for (int i = 0; i < 4; ++i) {
      int rb = wr + i * 16 + lq * 4;
#pragma unroll
      for (int p = 0; p < 4; ++p) {
        int r = rb + p;
        if (r < vr) {
          float* orow = ob + (size_t)(r0 + rowbase + r) * DDIM + colbase;
#pragma unroll
          for (int j = 0; j < 4; ++j) {
            int col = wc + j * 16 + l15;
            orow[col] = acc[i][j][p] + (split == 0 ? bp[col] : 0.f);
          }
        }
      }
    }
  }
}

// ---------------- K5: gated combine (splits + experts), writes y fully ----------------
__global__ __launch_bounds__(256) void combine_kernel(
    const float* __restrict__ outbuf, const int* __restrict__ posmap,
    const float* __restrict__ slotgate, float* __restrict__ y)
{
  int s = blockIdx.x;
  int tid = threadIdx.x;
  float a0 = 0.f, a1 = 0.f, a2 = 0.f;
#pragma unroll
  for (int e = 0; e < NEXP; ++e) {
    int p = posmap[e * S_TOK + s];
    if (p >= 0) {
      float g = slotgate[p];
      const float* o0 = outbuf + (size_t)p * DDIM;
      const float* o1 = outbuf + ((size_t)KSEL + p) * DDIM;
      a0 += g * (o0[tid] + o1[tid]);
      a1 += g * (o0[tid + 256] + o1[tid + 256]);
      a2 += g * (o0[tid + 512] + o1[tid + 512]);
    }
  }
  float* yr = y + (size_t)s * DDIM;
  yr[tid] = a0;
  yr[tid + 256] = a1;
  yr[tid + 512] = a2;
}

extern "C" void kernel_launch(void* const* d_in, const int* in_sizes, int n_in,
                              void* d_out, int out_size, void* d_ws, size_t ws_size,
                              hipStream_t stream) {
  const float* x  = (const float*)d_in[0];
  const float* gw = (const float*)d_in[1];
  const float* w1 = (const float*)d_in[2];
  const float* b1 = (const float*)d_in[3];
  const float* w2 = (const float*)d_in[4];
  const float* b2 = (const float*)d_in[5];
  float* y = (float*)d_out;

  char* ws = (char*)d_ws;
  float* scores    = (float*)(ws);                    // 64 KB
  int*   tokenlist = (int*)(ws + (64 << 10));         // 16 KB
  float* slotgate  = (float*)(ws + (80 << 10));       // 16 KB
  int*   offsets   = (int*)(ws + (96 << 10));         // 9 ints
  int*   posmap    = (int*)(ws + (128 << 10));        // 64 KB
  short* xbf       = (short*)(ws + (192 << 10));      // 3 MB
  short* hbuf      = (short*)(ws + (192 << 10) + (size_t)S_TOK * DDIM * 2);          // 24 MB
  float* outbuf    = (float*)(ws + (192 << 10) + (size_t)S_TOK * DDIM * 2
                                  + (size_t)KSEL * HDIM * 2);                        // 25.2 MB

  convx_kernel<<<S_TOK * DDIM / 2048, 256, 0, stream>>>(x, xbf);
  gate_kernel<<<S_TOK / 4, 256, 0, stream>>>(x, gw, scores);
  select_kernel<<<1, 1024, 0, stream>>>(scores, tokenlist, slotgate, offsets, posmap);

  dim3 g1(NEXP, HDIM / 128, 16);   // expert fastest -> id%8 == expert (XCD affinity)
  moe_mfma<1><<<g1, 256, 0, stream>>>(xbf, w1, b1, hbuf, offsets, tokenlist);
  dim3 g2(NEXP, DDIM / 128, 32);   // z = tile*2 + ksplit
  moe_mfma<2><<<g2, 256, 0, stream>>>(hbuf, w2, b2, outbuf, offsets, tokenlist);

  combine_kernel<<<S_TOK, 256, 0, stream>>>(outbuf, posmap, slotgate, y);
}